// Round 2
// baseline (653.139 us; speedup 1.0000x reference)
//
#include <hip/hip_runtime.h>
#include <hip/hip_bf16.h>

typedef __attribute__((ext_vector_type(8))) short short8;
typedef __attribute__((ext_vector_type(4))) float f32x4;

#define EPSV 1e-5f

__device__ __forceinline__ float bf2f(ushort u){
  union { uint i; float f; } x; x.i = ((uint)u) << 16; return x.f;
}
__device__ __forceinline__ ushort f2bf(float f){
  union { float f; uint i; } x; x.f = f;
  uint r = (x.i + 0x7FFFu + ((x.i >> 16) & 1u)) >> 16;
  return (ushort)r;
}

// ---------------- init: zero stats, max accumulators, row 0 of x1 ----------------
__global__ void init_kernel(ushort* x1, float* stats, int* maxbuf){
  int i = blockIdx.x * 256 + threadIdx.x;   // 32768 threads
  if (i < 384)  stats[i] = 0.f;
  if (i < 8192) maxbuf[i] = 0;
  if (i < 32768){ int b = i >> 9, c = i & 511; x1[(size_t)b*1025*512 + c] = 0; }
}

// ---------------- zero node-0 rows of x2 (AFTER aug is dead: aug aliases x2) ----------------
__global__ void zero2_kernel(ushort* x2){
  int i = blockIdx.x * 256 + threadIdx.x;   // 16384 threads
  int b = i >> 8, c = i & 255;
  x2[(size_t)b*1025*256 + c] = 0;
}

// ---------------- q_conv: 4 stacked linears, no activations ----------------
__global__ void qconv_kernel(const float* __restrict__ qv,
    const float* __restrict__ W1, const float* __restrict__ b1,
    const float* __restrict__ W2, const float* __restrict__ b2,
    const float* __restrict__ W3, const float* __restrict__ b3,
    const float* __restrict__ W4, const float* __restrict__ b4,
    float* __restrict__ qout){
  __shared__ float v0[96], h1[64], h2[128], h3[64];
  int b = blockIdx.x, t = threadIdx.x;
  if (t < 95) v0[t] = qv[b*95 + t];
  __syncthreads();
  if (t < 64){ float s = b1[t]; for (int i=0;i<95;i++)  s += v0[i]*W1[i*64 + t];  h1[t]=s; }
  __syncthreads();
  if (t < 128){ float s = b2[t]; for (int i=0;i<64;i++)  s += h1[i]*W2[i*128 + t]; h2[t]=s; }
  __syncthreads();
  if (t < 64){ float s = b3[t]; for (int i=0;i<128;i++) s += h2[i]*W3[i*64 + t];  h3[t]=s; }
  __syncthreads();
  if (t < 32){ float s = b4[t]; for (int i=0;i<64;i++)  s += h3[i]*W4[i*32 + t];  qout[b*32 + t]=s; }
}

// ---------------- build augmented input (B,1025,128) bf16 ----------------
__global__ void aug_kernel(const float* __restrict__ trees, const float* __restrict__ q,
                           ushort* __restrict__ aug){
  int n = blockIdx.x;            // 0..1024
  int b = blockIdx.y;            // 0..63
  int c = threadIdx.x;           // 0..127
  float v = (c < 96) ? trees[((size_t)b*1025 + n)*96 + c] : q[b*32 + (c - 96)];
  aug[(((size_t)b*1025 + n) << 7) + c] = f2bf(v);
}

// ---------------- weight transpose: Wt[o][kp*C+c] = Wc[o][c][kp], bf16 ----------------
__global__ void prepw_kernel(const float* __restrict__ wc, ushort* __restrict__ wt,
                             int O, int C){
  int i = blockIdx.x * 256 + threadIdx.x;
  int total = O * 3 * C;
  if (i >= total) return;
  int o  = i / (3*C);
  int K  = i - o*3*C;
  int kp = K / C;
  int c  = K - kp*C;
  wt[i] = f2bf(wc[(o*C + c)*3 + kp]);
}

// ---------------- gathered conv as MFMA GEMM ----------------
// xin: (B,1025,CIN) bf16 node-major.  wt: (COUT, 3*CIN) bf16.  out tile 64x64 per block.
template<int CIN, bool DO_MAX>
__global__ __launch_bounds__(256) void conv_kernel(
    const ushort* __restrict__ xin, const ushort* __restrict__ wt,
    const float* __restrict__ bias, const int* __restrict__ idxes,
    ushort* __restrict__ xout, float* __restrict__ stats, int* __restrict__ maxbuf){
  const int COUT = gridDim.y * 64;
  const int b  = blockIdx.z;
  const int m0 = blockIdx.x * 64;
  const int o0 = blockIdx.y * 64;
  const int t  = threadIdx.x;
  const int lane = t & 63, wid = t >> 6;
  const int wm = wid & 1, wo = wid >> 1;

  __shared__ __align__(16) ushort As[64][56];   // padded: conflict-free b128 reads
  __shared__ __align__(16) ushort Bs[64][56];
  __shared__ int idx_s[192];
  __shared__ __align__(8) ushort stage[64][68];

  if (t < 192) idx_s[t] = idxes[b*3072 + m0*3 + t];
  __syncthreads();

  f32x4 acc[2][2] = {};
  constexpr int CSTEPS = CIN / 32;
  constexpr int KSTEPS = 3 * CSTEPS;
  const int r = t >> 2, q = t & 3;
  const ushort* xb = xin + (size_t)b * 1025 * CIN;
  const int fr = lane & 15, fg = lane >> 4;

  for (int s = 0; s < KSTEPS; ++s){
    int kp = s / CSTEPS;
    int c0 = (s - kp*CSTEPS) * 32;
    int node = idx_s[r*3 + kp];
    uint4 av = *reinterpret_cast<const uint4*>(xb + node*CIN + c0 + q*8);
    uint4 bv = *reinterpret_cast<const uint4*>(wt + (size_t)(o0 + r)*(3*CIN) + s*32 + q*8);
    if (s) __syncthreads();
    *reinterpret_cast<uint4*>(&As[r][q*8]) = av;
    *reinterpret_cast<uint4*>(&Bs[r][q*8]) = bv;
    __syncthreads();
    short8 a0 = *reinterpret_cast<const short8*>(&As[wm*32 +      fr][fg*8]);
    short8 a1 = *reinterpret_cast<const short8*>(&As[wm*32 + 16 + fr][fg*8]);
    short8 b0 = *reinterpret_cast<const short8*>(&Bs[wo*32 +      fr][fg*8]);
    short8 b1 = *reinterpret_cast<const short8*>(&Bs[wo*32 + 16 + fr][fg*8]);
    acc[0][0] = __builtin_amdgcn_mfma_f32_16x16x32_bf16(a0, b0, acc[0][0], 0, 0, 0);
    acc[0][1] = __builtin_amdgcn_mfma_f32_16x16x32_bf16(a0, b1, acc[0][1], 0, 0, 0);
    acc[1][0] = __builtin_amdgcn_mfma_f32_16x16x32_bf16(a1, b0, acc[1][0], 0, 0, 0);
    acc[1][1] = __builtin_amdgcn_mfma_f32_16x16x32_bf16(a1, b1, acc[1][1], 0, 0, 0);
  }

  // ---- epilogue: bias, stats, optional max, optional store ----
  float bias0 = bias[o0 + wo*32 + fr];
  float bias1 = bias[o0 + wo*32 + 16 + fr];
  float lsum = 0.f, lsq = 0.f;
  float cmax[2] = { -1e30f, -1e30f };
  #pragma unroll
  for (int im = 0; im < 2; ++im){
    #pragma unroll
    for (int io = 0; io < 2; ++io){
      #pragma unroll
      for (int i = 0; i < 4; ++i){
        float v = acc[im][io][i] + (io ? bias1 : bias0);
        lsum += v; lsq += v*v;
        if (DO_MAX) cmax[io] = fmaxf(cmax[io], v);
        else stage[wm*32 + im*16 + fg*4 + i][wo*32 + io*16 + fr] = f2bf(v);
      }
    }
  }
  #pragma unroll
  for (int off = 1; off < 64; off <<= 1){
    lsum += __shfl_xor(lsum, off);
    lsq  += __shfl_xor(lsq,  off);
  }
  if (lane == 0){
    atomicAdd(&stats[b],      lsum);
    atomicAdd(&stats[64 + b], lsq);
  }
  if (DO_MAX){
    #pragma unroll
    for (int io = 0; io < 2; ++io){
      float v = cmax[io];
      v = fmaxf(v, __shfl_xor(v, 16));
      v = fmaxf(v, __shfl_xor(v, 32));
      if (lane < 16)
        atomicMax(&maxbuf[b*COUT + o0 + wo*32 + io*16 + fr], __float_as_int(v));
    }
  } else {
    __syncthreads();
    #pragma unroll
    for (int it = 0; it < 4; ++it){
      int row = it*16 + (t >> 4);
      int col = (t & 15) * 4;
      uint2 v = *reinterpret_cast<const uint2*>(&stage[row][col]);
      *reinterpret_cast<uint2*>(xout + ((size_t)(b*1025 + 1 + m0 + row))*COUT + o0 + col) = v;
    }
  }
}

// ---------------- in-place TreeLayerNorm + leaky_relu, bf16x8 vectorized ----------------
__global__ void norm_kernel(ushort* __restrict__ x, const float* __restrict__ st,
                            float cnt, int nvec_per_b){
  int b = blockIdx.y;
  int j = blockIdx.x * 256 + threadIdx.x;
  if (j >= nvec_per_b) return;
  float sum = st[b], sq = st[64 + b];
  float mean = sum / cnt;
  float var  = fmaxf((sq - sum*sum/cnt) / (cnt - 1.f), 0.f);
  float rs   = 1.f / (sqrtf(var) + EPSV);
  ushort* p = x + ((size_t)b * nvec_per_b + j) * 8;
  union { uint4 v; ushort u[8]; } d;
  d.v = *reinterpret_cast<const uint4*>(p);
  #pragma unroll
  for (int k = 0; k < 8; ++k){
    float f = bf2f(d.u[k]);
    f = (f - mean) * rs;
    f = (f >= 0.f) ? f : 0.01f * f;
    d.u[k] = f2bf(f);
  }
  *reinterpret_cast<uint4*>(p) = d.v;
}

// ---------------- final: normalize the per-channel max ----------------
__global__ void final_kernel(const int* __restrict__ maxbuf, const float* __restrict__ st,
                             float* __restrict__ out){
  int i = blockIdx.x * 256 + threadIdx.x;   // 8192
  int b = i >> 7;
  const float cnt = 131200.f;
  float sum = st[b], sq = st[64 + b];
  float mean = sum / cnt;
  float var  = fmaxf((sq - sum*sum/cnt) / (cnt - 1.f), 0.f);
  float rs   = 1.f / (sqrtf(var) + EPSV);
  out[i] = (__int_as_float(maxbuf[i]) - mean) * rs;
}

// ---------------- workspace layout ----------------
static constexpr size_t SZ_X1  = (size_t)64*1025*512*2;   // 67,174,400
static constexpr size_t SZ_X2  = (size_t)64*1025*256*2;   // 33,587,200
static constexpr size_t OFF_X1 = 0;
static constexpr size_t OFF_X2 = OFF_X1 + SZ_X1;
static constexpr size_t OFF_AUG = OFF_X2;                 // alias: aug dead after conv1
static constexpr size_t OFF_WT1 = OFF_X2 + SZ_X2;
static constexpr size_t OFF_WT2 = OFF_WT1 + (size_t)512*384*2;
static constexpr size_t OFF_WT3 = OFF_WT2 + (size_t)256*1536*2;
static constexpr size_t OFF_Q   = OFF_WT3 + (size_t)128*768*2;
static constexpr size_t OFF_ST  = OFF_Q + (size_t)64*32*4;
static constexpr size_t OFF_MAX = OFF_ST + (size_t)384*4;

extern "C" void kernel_launch(void* const* d_in, const int* in_sizes, int n_in,
                              void* d_out, int out_size, void* d_ws, size_t ws_size,
                              hipStream_t stream){
  const float* q_vecs = (const float*)d_in[0];
  const float* trees  = (const float*)d_in[1];
  const int*   idxes  = (const int*)  d_in[2];
  const float* Wq1 = (const float*)d_in[3];  const float* bq1 = (const float*)d_in[4];
  const float* Wq2 = (const float*)d_in[5];  const float* bq2 = (const float*)d_in[6];
  const float* Wq3 = (const float*)d_in[7];  const float* bq3 = (const float*)d_in[8];
  const float* Wq4 = (const float*)d_in[9];  const float* bq4 = (const float*)d_in[10];
  const float* Wc1 = (const float*)d_in[11]; const float* bc1 = (const float*)d_in[12];
  const float* Wc2 = (const float*)d_in[13]; const float* bc2 = (const float*)d_in[14];
  const float* Wc3 = (const float*)d_in[15]; const float* bc3 = (const float*)d_in[16];
  float* out = (float*)d_out;
  char* ws = (char*)d_ws;

  ushort* x1    = (ushort*)(ws + OFF_X1);
  ushort* x2    = (ushort*)(ws + OFF_X2);
  ushort* aug   = (ushort*)(ws + OFF_AUG);
  ushort* wt1   = (ushort*)(ws + OFF_WT1);
  ushort* wt2   = (ushort*)(ws + OFF_WT2);
  ushort* wt3   = (ushort*)(ws + OFF_WT3);
  float*  qbuf  = (float*) (ws + OFF_Q);
  float*  stats = (float*) (ws + OFF_ST);
  int*    maxb  = (int*)   (ws + OFF_MAX);

  init_kernel<<<128, 256, 0, stream>>>(x1, stats, maxb);
  qconv_kernel<<<64, 128, 0, stream>>>(q_vecs, Wq1,bq1, Wq2,bq2, Wq3,bq3, Wq4,bq4, qbuf);
  aug_kernel<<<dim3(1025, 64), 128, 0, stream>>>(trees, qbuf, aug);
  prepw_kernel<<<(512*384 + 255)/256, 256, 0, stream>>>(Wc1, wt1, 512, 128);
  prepw_kernel<<<(256*1536 + 255)/256, 256, 0, stream>>>(Wc2, wt2, 256, 512);
  prepw_kernel<<<(128*768 + 255)/256, 256, 0, stream>>>(Wc3, wt3, 128, 256);

  conv_kernel<128, false><<<dim3(16, 8, 64), 256, 0, stream>>>(aug, wt1, bc1, idxes, x1, stats +   0, nullptr);
  zero2_kernel<<<64, 256, 0, stream>>>(x2);   // aug (aliased with x2) is dead now
  norm_kernel<<<dim3((65600 + 255)/256, 64), 256, 0, stream>>>(x1, stats +   0, 524800.f, 65600);
  conv_kernel<512, false><<<dim3(16, 4, 64), 256, 0, stream>>>(x1,  wt2, bc2, idxes, x2, stats + 128, nullptr);
  norm_kernel<<<dim3((32800 + 255)/256, 64), 256, 0, stream>>>(x2, stats + 128, 262400.f, 32800);
  conv_kernel<256, true ><<<dim3(16, 2, 64), 256, 0, stream>>>(x2,  wt3, bc3, idxes, nullptr, stats + 256, maxb);
  final_kernel<<<32, 256, 0, stream>>>(maxb, stats + 256, out);
}

// Round 3
// 318.464 us; speedup vs baseline: 2.0509x; 2.0509x over previous
//
#include <hip/hip_runtime.h>
#include <hip/hip_bf16.h>

typedef __attribute__((ext_vector_type(8))) short short8;
typedef __attribute__((ext_vector_type(4))) float f32x4;

#define EPSV 1e-5f

__device__ __forceinline__ float bf2f(ushort u){
  union { uint i; float f; } x; x.i = ((uint)u) << 16; return x.f;
}
__device__ __forceinline__ ushort f2bf(float f){
  union { float f; uint i; } x; x.f = f;
  uint r = (x.i + 0x7FFFu + ((x.i >> 16) & 1u)) >> 16;
  return (ushort)r;
}

// ---------------- init: zero stats, max accumulators, row 0 of x1 ----------------
__global__ void init_kernel(ushort* x1, float* stats, int* maxbuf){
  int i = blockIdx.x * 256 + threadIdx.x;   // 32768 threads
  if (i < 384)  stats[i] = 0.f;
  if (i < 8192) maxbuf[i] = 0;
  if (i < 32768){ int b = i >> 9, c = i & 511; x1[(size_t)b*1025*512 + c] = 0; }
}

// ---------------- zero node-0 rows of x2 (AFTER aug is dead: aug aliases x2) ----------------
__global__ void zero2_kernel(ushort* x2){
  int i = blockIdx.x * 256 + threadIdx.x;   // 16384 threads
  int b = i >> 8, c = i & 255;
  x2[(size_t)b*1025*256 + c] = 0;
}

// ---------------- q_conv: 4 stacked linears, no activations ----------------
__global__ void qconv_kernel(const float* __restrict__ qv,
    const float* __restrict__ W1, const float* __restrict__ b1,
    const float* __restrict__ W2, const float* __restrict__ b2,
    const float* __restrict__ W3, const float* __restrict__ b3,
    const float* __restrict__ W4, const float* __restrict__ b4,
    float* __restrict__ qout){
  __shared__ float v0[96], h1[64], h2[128], h3[64];
  int b = blockIdx.x, t = threadIdx.x;
  if (t < 95) v0[t] = qv[b*95 + t];
  __syncthreads();
  if (t < 64){ float s = b1[t]; for (int i=0;i<95;i++)  s += v0[i]*W1[i*64 + t];  h1[t]=s; }
  __syncthreads();
  if (t < 128){ float s = b2[t]; for (int i=0;i<64;i++)  s += h1[i]*W2[i*128 + t]; h2[t]=s; }
  __syncthreads();
  if (t < 64){ float s = b3[t]; for (int i=0;i<128;i++) s += h2[i]*W3[i*64 + t];  h3[t]=s; }
  __syncthreads();
  if (t < 32){ float s = b4[t]; for (int i=0;i<64;i++)  s += h3[i]*W4[i*32 + t];  qout[b*32 + t]=s; }
}

// ---------------- build augmented input (B,1025,128) bf16 ----------------
__global__ void aug_kernel(const float* __restrict__ trees, const float* __restrict__ q,
                           ushort* __restrict__ aug){
  int n = blockIdx.x;            // 0..1024
  int b = blockIdx.y;            // 0..63
  int c = threadIdx.x;           // 0..127
  float v = (c < 96) ? trees[((size_t)b*1025 + n)*96 + c] : q[b*32 + (c - 96)];
  aug[(((size_t)b*1025 + n) << 7) + c] = f2bf(v);
}

// ---------------- weight transpose: Wt[o][kp*C+c] = Wc[o][c][kp], bf16 ----------------
__global__ void prepw_kernel(const float* __restrict__ wc, ushort* __restrict__ wt,
                             int O, int C){
  int i = blockIdx.x * 256 + threadIdx.x;
  int total = O * 3 * C;
  if (i >= total) return;
  int o  = i / (3*C);
  int K  = i - o*3*C;
  int kp = K / C;
  int c  = K - kp*C;
  wt[i] = f2bf(wc[(o*C + c)*3 + kp]);
}

// ---------------- gathered conv as MFMA GEMM, 128x128 tile, 2-phase dbuf ----------------
// xin: (B,1025,CIN) bf16 node-major.  wt: (COUT, 3*CIN) bf16.
template<int CIN, bool DO_MAX>
__global__ __launch_bounds__(256) void conv_kernel(
    const ushort* __restrict__ xin, const ushort* __restrict__ wt,
    const float* __restrict__ bias, const int* __restrict__ idxes,
    ushort* __restrict__ xout, float* __restrict__ stats, int* __restrict__ maxbuf){
  constexpr int K3 = 3 * CIN;
  constexpr int NT = K3 / 32;          // K-chunks of 32
  const int COUT = gridDim.y * 128;
  const int b  = blockIdx.z;
  const int m0 = blockIdx.x * 128;
  const int o0 = blockIdx.y * 128;
  const int t  = threadIdx.x;
  const int lane = t & 63, wid = t >> 6;
  const int WM = (wid & 1) * 64, WO = (wid >> 1) * 64;
  const int fr = lane & 15, fg = lane >> 4;

  // padded rows: stride 40 ushort = 20 dwords, gcd(20,32)=4 -> 2-way max on b128 reads
  __shared__ __align__(16) union {
    struct { ushort A[2][128][40]; ushort B[2][128][40]; } s;
    ushort stage[128][132];
  } sh;
  __shared__ int idx_s[384];

  for (int i = t; i < 384; i += 256) idx_s[i] = idxes[b*3072 + m0*3 + i];
  __syncthreads();

  const ushort* xb = xin + (size_t)b * 1025 * CIN;
  const int rr = t >> 1, cb = (t & 1) * 16;   // each thread stages 32B of A and 32B of B

  uint4 ra0, ra1, rb0, rb1;
  auto GLOAD = [&](int ch){
    int k0 = ch * 32;
    int kp = k0 / CIN;
    int c  = k0 - kp * CIN;
    int node = idx_s[rr*3 + kp];
    const ushort* sa = xb + (size_t)node * CIN + c + cb;
    ra0 = *reinterpret_cast<const uint4*>(sa);
    ra1 = *reinterpret_cast<const uint4*>(sa + 8);
    const ushort* sb = wt + (size_t)(o0 + rr) * K3 + k0 + cb;
    rb0 = *reinterpret_cast<const uint4*>(sb);
    rb1 = *reinterpret_cast<const uint4*>(sb + 8);
  };
  auto DSW = [&](int bf){
    *reinterpret_cast<uint4*>(&sh.s.A[bf][rr][cb])     = ra0;
    *reinterpret_cast<uint4*>(&sh.s.A[bf][rr][cb + 8]) = ra1;
    *reinterpret_cast<uint4*>(&sh.s.B[bf][rr][cb])     = rb0;
    *reinterpret_cast<uint4*>(&sh.s.B[bf][rr][cb + 8]) = rb1;
  };

  f32x4 acc[4][4] = {};

  GLOAD(0);
  DSW(0);
  __syncthreads();
  int cur = 0;
  for (int ch = 0; ch < NT; ++ch){
    if (ch + 1 < NT) GLOAD(ch + 1);            // issue next-chunk loads early
    short8 af[4], bfr[4];
    #pragma unroll
    for (int i = 0; i < 4; ++i){
      af[i]  = *reinterpret_cast<const short8*>(&sh.s.A[cur][WM + i*16 + fr][fg*8]);
      bfr[i] = *reinterpret_cast<const short8*>(&sh.s.B[cur][WO + i*16 + fr][fg*8]);
    }
    #pragma unroll
    for (int mf = 0; mf < 4; ++mf)
      #pragma unroll
      for (int nf = 0; nf < 4; ++nf)
        acc[mf][nf] = __builtin_amdgcn_mfma_f32_16x16x32_bf16(af[mf], bfr[nf], acc[mf][nf], 0, 0, 0);
    if (ch + 1 < NT){
      DSW(cur ^ 1);                            // vmcnt wait lands here, hidden by MFMAs
      __syncthreads();                         // single barrier per chunk
      cur ^= 1;
    }
  }

  // ---- epilogue: bias, stats, optional max, optional store ----
  float bsv[4];
  #pragma unroll
  for (int nf = 0; nf < 4; ++nf) bsv[nf] = bias[o0 + WO + nf*16 + fr];
  float lsum = 0.f, lsq = 0.f;
  float cmax[4] = { -1e30f, -1e30f, -1e30f, -1e30f };
  #pragma unroll
  for (int mf = 0; mf < 4; ++mf)
    #pragma unroll
    for (int nf = 0; nf < 4; ++nf)
      #pragma unroll
      for (int i = 0; i < 4; ++i){
        float v = acc[mf][nf][i] + bsv[nf];
        lsum += v; lsq += v*v;
        if (DO_MAX) cmax[nf] = fmaxf(cmax[nf], v);
        else acc[mf][nf][i] = v;
      }
  #pragma unroll
  for (int off = 1; off < 64; off <<= 1){
    lsum += __shfl_xor(lsum, off);
    lsq  += __shfl_xor(lsq,  off);
  }
  if (lane == 0){
    atomicAdd(&stats[b],      lsum);
    atomicAdd(&stats[64 + b], lsq);
  }
  if (DO_MAX){
    #pragma unroll
    for (int nf = 0; nf < 4; ++nf){
      float v = cmax[nf];
      v = fmaxf(v, __shfl_xor(v, 16));
      v = fmaxf(v, __shfl_xor(v, 32));
      if (lane < 16)
        atomicMax(&maxbuf[b*COUT + o0 + WO + nf*16 + fr], __float_as_int(v));
    }
  } else {
    __syncthreads();   // all waves done with K-buffers; reuse as staging
    #pragma unroll
    for (int mf = 0; mf < 4; ++mf)
      #pragma unroll
      for (int nf = 0; nf < 4; ++nf)
        #pragma unroll
        for (int i = 0; i < 4; ++i)
          sh.stage[WM + mf*16 + fg*4 + i][WO + nf*16 + fr] = f2bf(acc[mf][nf][i]);
    __syncthreads();
    #pragma unroll
    for (int it = 0; it < 16; ++it){
      int row = it*8 + (t >> 5);
      int col = (t & 31) * 4;
      uint2 v = *reinterpret_cast<const uint2*>(&sh.stage[row][col]);
      *reinterpret_cast<uint2*>(xout + ((size_t)(b*1025 + 1 + m0 + row))*COUT + o0 + col) = v;
    }
  }
}

// ---------------- in-place TreeLayerNorm + leaky_relu, bf16x8 vectorized ----------------
__global__ void norm_kernel(ushort* __restrict__ x, const float* __restrict__ st,
                            float cnt, int nvec_per_b){
  int b = blockIdx.y;
  int j = blockIdx.x * 256 + threadIdx.x;
  if (j >= nvec_per_b) return;
  float sum = st[b], sq = st[64 + b];
  float mean = sum / cnt;
  float var  = fmaxf((sq - sum*sum/cnt) / (cnt - 1.f), 0.f);
  float rs   = 1.f / (sqrtf(var) + EPSV);
  ushort* p = x + ((size_t)b * nvec_per_b + j) * 8;
  union { uint4 v; ushort u[8]; } d;
  d.v = *reinterpret_cast<const uint4*>(p);
  #pragma unroll
  for (int k = 0; k < 8; ++k){
    float f = bf2f(d.u[k]);
    f = (f - mean) * rs;
    f = (f >= 0.f) ? f : 0.01f * f;
    d.u[k] = f2bf(f);
  }
  *reinterpret_cast<uint4*>(p) = d.v;
}

// ---------------- final: normalize the per-channel max ----------------
__global__ void final_kernel(const int* __restrict__ maxbuf, const float* __restrict__ st,
                             float* __restrict__ out){
  int i = blockIdx.x * 256 + threadIdx.x;   // 8192
  int b = i >> 7;
  const float cnt = 131200.f;
  float sum = st[b], sq = st[64 + b];
  float mean = sum / cnt;
  float var  = fmaxf((sq - sum*sum/cnt) / (cnt - 1.f), 0.f);
  float rs   = 1.f / (sqrtf(var) + EPSV);
  out[i] = (__int_as_float(maxbuf[i]) - mean) * rs;
}

// ---------------- workspace layout ----------------
static constexpr size_t SZ_X1  = (size_t)64*1025*512*2;   // 67,174,400
static constexpr size_t SZ_X2  = (size_t)64*1025*256*2;   // 33,587,200
static constexpr size_t OFF_X1 = 0;
static constexpr size_t OFF_X2 = OFF_X1 + SZ_X1;
static constexpr size_t OFF_AUG = OFF_X2;                 // alias: aug dead after conv1
static constexpr size_t OFF_WT1 = OFF_X2 + SZ_X2;
static constexpr size_t OFF_WT2 = OFF_WT1 + (size_t)512*384*2;
static constexpr size_t OFF_WT3 = OFF_WT2 + (size_t)256*1536*2;
static constexpr size_t OFF_Q   = OFF_WT3 + (size_t)128*768*2;
static constexpr size_t OFF_ST  = OFF_Q + (size_t)64*32*4;
static constexpr size_t OFF_MAX = OFF_ST + (size_t)384*4;

extern "C" void kernel_launch(void* const* d_in, const int* in_sizes, int n_in,
                              void* d_out, int out_size, void* d_ws, size_t ws_size,
                              hipStream_t stream){
  const float* q_vecs = (const float*)d_in[0];
  const float* trees  = (const float*)d_in[1];
  const int*   idxes  = (const int*)  d_in[2];
  const float* Wq1 = (const float*)d_in[3];  const float* bq1 = (const float*)d_in[4];
  const float* Wq2 = (const float*)d_in[5];  const float* bq2 = (const float*)d_in[6];
  const float* Wq3 = (const float*)d_in[7];  const float* bq3 = (const float*)d_in[8];
  const float* Wq4 = (const float*)d_in[9];  const float* bq4 = (const float*)d_in[10];
  const float* Wc1 = (const float*)d_in[11]; const float* bc1 = (const float*)d_in[12];
  const float* Wc2 = (const float*)d_in[13]; const float* bc2 = (const float*)d_in[14];
  const float* Wc3 = (const float*)d_in[15]; const float* bc3 = (const float*)d_in[16];
  float* out = (float*)d_out;
  char* ws = (char*)d_ws;

  ushort* x1    = (ushort*)(ws + OFF_X1);
  ushort* x2    = (ushort*)(ws + OFF_X2);
  ushort* aug   = (ushort*)(ws + OFF_AUG);
  ushort* wt1   = (ushort*)(ws + OFF_WT1);
  ushort* wt2   = (ushort*)(ws + OFF_WT2);
  ushort* wt3   = (ushort*)(ws + OFF_WT3);
  float*  qbuf  = (float*) (ws + OFF_Q);
  float*  stats = (float*) (ws + OFF_ST);
  int*    maxb  = (int*)   (ws + OFF_MAX);

  init_kernel<<<128, 256, 0, stream>>>(x1, stats, maxb);
  qconv_kernel<<<64, 128, 0, stream>>>(q_vecs, Wq1,bq1, Wq2,bq2, Wq3,bq3, Wq4,bq4, qbuf);
  aug_kernel<<<dim3(1025, 64), 128, 0, stream>>>(trees, qbuf, aug);
  prepw_kernel<<<(512*384 + 255)/256, 256, 0, stream>>>(Wc1, wt1, 512, 128);
  prepw_kernel<<<(256*1536 + 255)/256, 256, 0, stream>>>(Wc2, wt2, 256, 512);
  prepw_kernel<<<(128*768 + 255)/256, 256, 0, stream>>>(Wc3, wt3, 128, 256);

  conv_kernel<128, false><<<dim3(8, 4, 64), 256, 0, stream>>>(aug, wt1, bc1, idxes, x1, stats +   0, nullptr);
  zero2_kernel<<<64, 256, 0, stream>>>(x2);   // aug (aliased with x2) is dead now
  norm_kernel<<<dim3((65600 + 255)/256, 64), 256, 0, stream>>>(x1, stats +   0, 524800.f, 65600);
  conv_kernel<512, false><<<dim3(8, 2, 64), 256, 0, stream>>>(x1,  wt2, bc2, idxes, x2, stats + 128, nullptr);
  norm_kernel<<<dim3((32800 + 255)/256, 64), 256, 0, stream>>>(x2, stats + 128, 262400.f, 32800);
  conv_kernel<256, true ><<<dim3(8, 1, 64), 256, 0, stream>>>(x2,  wt3, bc3, idxes, nullptr, stats + 256, maxb);
  final_kernel<<<32, 256, 0, stream>>>(maxb, stats + 256, out);
}